// Round 1
// baseline (341.761 us; speedup 1.0000x reference)
//
#include <hip/hip_runtime.h>
#include <stdint.h>

// Problem constants: B=4, T=2048, D=1024, NH=16, DH=64
#define TSEQ   2048
#define SCALE_ATTN 0.125f

typedef __attribute__((ext_vector_type(8))) short bf16x8;   // 8 bf16 = 4 VGPRs (MFMA A/B frag)
typedef __attribute__((ext_vector_type(4))) short short4v;
typedef __attribute__((ext_vector_type(4))) float f32x4;    // MFMA C/D frag

__device__ __forceinline__ short f2bf(float f) {  // RNE float->bf16 (finite inputs)
  unsigned u = __float_as_uint(f);
  u = (u + 0x7fffu + ((u >> 16) & 1u)) >> 16;
  return (short)u;
}

__device__ __forceinline__ void async16(const void* gsrc, void* ldst) {
  // global -> LDS direct, 16B per lane; LDS dest must be wave-uniform-base + lane*16
  __builtin_amdgcn_global_load_lds((__attribute__((address_space(1))) void*)(void*)gsrc,
                                   (__attribute__((address_space(3))) void*)ldst, 16, 0, 0);
}

// ---------------------------------------------------------------------------
// cast fp32 -> bf16 (bits in short), vectorized 4/thread
// ---------------------------------------------------------------------------
__global__ void cast_f32_bf16(const float* __restrict__ src, short* __restrict__ dst, int n) {
  int i = (blockIdx.x * blockDim.x + threadIdx.x) * 4;
  if (i >= n) return;
  float4 v = *(const float4*)(src + i);
  short4v o;
  o[0] = f2bf(v.x); o[1] = f2bf(v.y); o[2] = f2bf(v.z); o[3] = f2bf(v.w);
  *(short4v*)(dst + i) = o;
}

// ---------------------------------------------------------------------------
// C[M,N] = A[M,K] @ B[N,K]^T   (bf16 in, fp32 acc)
// OUTBF16=1: C bf16 (short). OUTBF16=0: C fp32 + bias[col].
// BM=BN=128, BK=64, 4 waves (2x2), 16x16x32 MFMA, XOR-swizzled LDS.
// Requires M%128==0, N%128==0, K%64==0, gridDim.x == (M/128)*(N/128).
// ---------------------------------------------------------------------------
template<int OUTBF16>
__global__ __launch_bounds__(256, 2) void gemm_bt(
    const short* __restrict__ A, const short* __restrict__ B,
    void* __restrict__ C, const float* __restrict__ bias,
    int M, int N, int K)
{
  __shared__ char ldsA[128 * 128];
  __shared__ char ldsB[128 * 128];

  const int tid  = threadIdx.x;
  const int lane = tid & 63;
  const int w    = tid >> 6;
  const int wrow = w >> 1, wcol = w & 1;
  const int l15  = lane & 15;
  const int klo  = (lane >> 4) << 4;      // byte offset of lane-group within 64B

  // XCD-bijective swizzle (m204); nwg%8==0 for both our launches
  int nwg = gridDim.x, orig = blockIdx.x;
  int qq = nwg >> 3, rr = nwg & 7;
  int xcd = orig & 7, lid = orig >> 3;
  int wgid = (xcd < rr ? xcd * (qq + 1) : rr * (qq + 1) + (xcd - rr) * qq) + lid;
  const int nbx = N >> 7;
  const int by = wgid / nbx, bx = wgid - by * nbx;
  const int m0 = by << 7, n0 = bx << 7;

  const char* Abase = (const char*)A + (size_t)m0 * K * 2;
  const char* Bbase = (const char*)B + (size_t)n0 * K * 2;
  const int rowstride = K * 2;

  const int srow  = tid >> 3;            // 0..31
  const int scolb = (tid & 7) << 4;      // 0..112

  f32x4 acc[4][4] = {};

  const int nk = K >> 6;
  for (int kk = 0; kk < nk; ++kk) {
    if (kk) __syncthreads();             // all waves done reading previous tiles
    const int kbyte = kk << 7;
    #pragma unroll
    for (int p = 0; p < 4; ++p) {        // 4 passes x 32 rows: full 128x128B tile
      int row = p * 32 + srow;
      int sc  = scolb ^ ((row & 7) << 4);     // pre-swizzled global source (rule #21)
      async16(Abase + (size_t)row * rowstride + kbyte + sc, ldsA + row * 128 + scolb);
      async16(Bbase + (size_t)row * rowstride + kbyte + sc, ldsB + row * 128 + scolb);
    }
    __syncthreads();                     // drains vmcnt -> tiles ready

    bf16x8 af[2][4], bf[2][4];
    #pragma unroll
    for (int ks = 0; ks < 2; ++ks)
      #pragma unroll
      for (int mi = 0; mi < 4; ++mi) {
        int row = wrow * 64 + mi * 16 + l15;
        af[ks][mi] = *(const bf16x8*)(ldsA + row * 128 + ((ks * 64 + klo) ^ ((row & 7) << 4)));
      }
    #pragma unroll
    for (int ks = 0; ks < 2; ++ks)
      #pragma unroll
      for (int ni = 0; ni < 4; ++ni) {
        int row = wcol * 64 + ni * 16 + l15;
        bf[ks][ni] = *(const bf16x8*)(ldsB + row * 128 + ((ks * 64 + klo) ^ ((row & 7) << 4)));
      }
    #pragma unroll
    for (int mi = 0; mi < 4; ++mi)
      #pragma unroll
      for (int ni = 0; ni < 4; ++ni) {
        acc[mi][ni] = __builtin_amdgcn_mfma_f32_16x16x32_bf16(af[0][mi], bf[0][ni], acc[mi][ni], 0, 0, 0);
        acc[mi][ni] = __builtin_amdgcn_mfma_f32_16x16x32_bf16(af[1][mi], bf[1][ni], acc[mi][ni], 0, 0, 0);
      }
  }

  // epilogue: C/D layout col=lane&15, row=(lane>>4)*4+j  [m89]
  const int rbase = (lane >> 4) << 2;
  #pragma unroll
  for (int mi = 0; mi < 4; ++mi)
    #pragma unroll
    for (int ni = 0; ni < 4; ++ni) {
      int col = n0 + wcol * 64 + ni * 16 + l15;
      #pragma unroll
      for (int j = 0; j < 4; ++j) {
        int row = m0 + wrow * 64 + mi * 16 + rbase + j;
        float v = acc[mi][ni][j];
        if (OUTBF16) ((short*)C)[(size_t)row * N + col] = f2bf(v);
        else         ((float*)C)[(size_t)row * N + col] = v + bias[col];
      }
    }
}

// ---------------------------------------------------------------------------
// Causal flash attention. qkv: [B*T][3072] bf16 (q|k|v each 1024 = 16 heads x 64)
// O: [B*T][1024] bf16, layout [b,t,h,dh]. Block = (qt, bh): 128 Q-rows, 4 waves
// x 32 rows each; KV tiles of 64.
// ---------------------------------------------------------------------------
__global__ __launch_bounds__(256, 2) void attn_fwd(
    const short* __restrict__ qkv, short* __restrict__ O)
{
  __shared__ char  ldsQ[128 * 128];      // swizzled, 128 q-rows x 64 dh
  __shared__ char  ldsK[64 * 128];       // swizzled, 64 kv-rows x 64 dh
  __shared__ short ldsVt[64][72];        // V transposed: [dh][kv], +8 pad -> 2-way banks
  __shared__ short ldsP[4][32][72];      // per-wave P: [qrow][kv], 144B rows (16B-aligned)

  const int tid  = threadIdx.x;
  const int lane = tid & 63;
  const int w    = tid >> 6;
  const int qt   = blockIdx.x;           // 0..15
  const int bh   = blockIdx.y;           // 0..63
  const int b    = bh >> 4, h = bh & 15;
  const int q0   = qt * 128;
  const int rowbase = b * TSEQ;
  const int l15  = lane & 15;
  const int lg   = lane >> 4;
  const int klo  = lg << 4;

  // stage Q tile (swizzled)
  {
    const int srow = tid >> 3, scolb = (tid & 7) << 4;
    #pragma unroll
    for (int p = 0; p < 4; ++p) {
      int row = p * 32 + srow;
      int sc = scolb ^ ((row & 7) << 4);
      async16((const char*)qkv + ((size_t)(rowbase + q0 + row) * 3072 + h * 64) * 2 + sc,
              ldsQ + row * 128 + scolb);
    }
  }
  __syncthreads();

  bf16x8 qf[2][2];                       // Q frags live in registers for whole kernel
  #pragma unroll
  for (int ks = 0; ks < 2; ++ks)
    #pragma unroll
    for (int mi = 0; mi < 2; ++mi) {
      int row = w * 32 + mi * 16 + l15;
      qf[ks][mi] = *(const bf16x8*)(ldsQ + row * 128 + ((ks * 64 + klo) ^ ((row & 7) << 4)));
    }

  f32x4 oacc[2][4] = {};
  float mrun[2][4], lrun[2][4];
  #pragma unroll
  for (int mi = 0; mi < 2; ++mi)
    #pragma unroll
    for (int j = 0; j < 4; ++j) { mrun[mi][j] = -1e30f; lrun[mi][j] = 0.f; }

  const int nsteps = 2 * qt + 2;
  for (int s = 0; s < nsteps; ++s) {
    const int kv0 = s * 64;
    const bool diag = (s >= nsteps - 2); // uniform

    __syncthreads();                     // previous K/Vt fully consumed
    {
      const int srow = tid >> 3, scolb = (tid & 7) << 4;
      #pragma unroll
      for (int p = 0; p < 2; ++p) {      // K tile: 64 rows x 128B, swizzled
        int row = p * 32 + srow;
        int sc = scolb ^ ((row & 7) << 4);
        async16((const char*)qkv + ((size_t)(rowbase + kv0 + row) * 3072 + 1024 + h * 64) * 2 + sc,
                ldsK + row * 128 + scolb);
      }
      const int vr = tid >> 3, vc0 = (tid & 7) << 3;
      #pragma unroll
      for (int p = 0; p < 2; ++p) {      // V tile transposed via reg round-trip
        int r = p * 32 + vr;
        bf16x8 vv = *(const bf16x8*)(qkv + (size_t)(rowbase + kv0 + r) * 3072 + 2048 + h * 64 + vc0);
        #pragma unroll
        for (int j = 0; j < 8; ++j) ldsVt[vc0 + j][r] = vv[j];
      }
    }
    __syncthreads();                     // K/Vt ready (vmcnt drained)

    // S = Q K^T
    bf16x8 kf[2][4];
    #pragma unroll
    for (int ks = 0; ks < 2; ++ks)
      #pragma unroll
      for (int ni = 0; ni < 4; ++ni) {
        int row = ni * 16 + l15;
        kf[ks][ni] = *(const bf16x8*)(ldsK + row * 128 + ((ks * 64 + klo) ^ ((row & 7) << 4)));
      }
    f32x4 sacc[2][4] = {};
    #pragma unroll
    for (int mi = 0; mi < 2; ++mi)
      #pragma unroll
      for (int ni = 0; ni < 4; ++ni) {
        sacc[mi][ni] = __builtin_amdgcn_mfma_f32_16x16x32_bf16(qf[0][mi], kf[0][ni], sacc[mi][ni], 0, 0, 0);
        sacc[mi][ni] = __builtin_amdgcn_mfma_f32_16x16x32_bf16(qf[1][mi], kf[1][ni], sacc[mi][ni], 0, 0, 0);
      }

    // scale + causal mask (S rows: q = q0+w*32+mi*16+lg*4+j ; cols: kv0+ni*16+l15)
    #pragma unroll
    for (int mi = 0; mi < 2; ++mi)
      #pragma unroll
      for (int ni = 0; ni < 4; ++ni)
        #pragma unroll
        for (int j = 0; j < 4; ++j) {
          float sv = sacc[mi][ni][j] * SCALE_ATTN;
          if (diag) {
            int qrow = q0 + w * 32 + mi * 16 + lg * 4 + j;
            int kcol = kv0 + ni * 16 + l15;
            if (kcol > qrow) sv = -1e30f;
          }
          sacc[mi][ni][j] = sv;
        }

    // wave-parallel row max (16-lane column group shares a row)
    float rmx[2][4];
    #pragma unroll
    for (int mi = 0; mi < 2; ++mi)
      #pragma unroll
      for (int j = 0; j < 4; ++j) {
        float v = fmaxf(fmaxf(sacc[mi][0][j], sacc[mi][1][j]), fmaxf(sacc[mi][2][j], sacc[mi][3][j]));
        v = fmaxf(v, __shfl_xor(v, 1));
        v = fmaxf(v, __shfl_xor(v, 2));
        v = fmaxf(v, __shfl_xor(v, 4));
        v = fmaxf(v, __shfl_xor(v, 8));
        rmx[mi][j] = v;
      }

    // online-softmax update: rescale O, emit P (bf16) into per-wave LDS
    #pragma unroll
    for (int mi = 0; mi < 2; ++mi)
      #pragma unroll
      for (int j = 0; j < 4; ++j) {
        float mold = mrun[mi][j];
        float mnew = fmaxf(mold, rmx[mi][j]);
        float alpha = __expf(mold - mnew);
        mrun[mi][j] = mnew;
        float rs = 0.f;
        #pragma unroll
        for (int ni = 0; ni < 4; ++ni) {
          float p = __expf(sacc[mi][ni][j] - mnew);
          rs += p;
          ldsP[w][mi * 16 + lg * 4 + j][ni * 16 + l15] = f2bf(p);
        }
        rs += __shfl_xor(rs, 1); rs += __shfl_xor(rs, 2);
        rs += __shfl_xor(rs, 4); rs += __shfl_xor(rs, 8);
        lrun[mi][j] = lrun[mi][j] * alpha + rs;
        #pragma unroll
        for (int ni = 0; ni < 4; ++ni) oacc[mi][ni][j] *= alpha;
      }

    asm volatile("" ::: "memory");       // keep P stores before P loads (HW runs DS in order)

    // O += P @ V
    bf16x8 pf[2][2], vf[2][4];
    #pragma unroll
    for (int ks = 0; ks < 2; ++ks)
      #pragma unroll
      for (int mi = 0; mi < 2; ++mi)
        pf[ks][mi] = *(const bf16x8*)((const char*)&ldsP[w][mi * 16 + l15][0] + ks * 64 + klo);
    #pragma unroll
    for (int ks = 0; ks < 2; ++ks)
      #pragma unroll
      for (int ni = 0; ni < 4; ++ni)
        vf[ks][ni] = *(const bf16x8*)((const char*)&ldsVt[ni * 16 + l15][0] + ks * 64 + klo);
    #pragma unroll
    for (int mi = 0; mi < 2; ++mi)
      #pragma unroll
      for (int ni = 0; ni < 4; ++ni) {
        oacc[mi][ni] = __builtin_amdgcn_mfma_f32_16x16x32_bf16(pf[0][mi], vf[0][ni], oacc[mi][ni], 0, 0, 0);
        oacc[mi][ni] = __builtin_amdgcn_mfma_f32_16x16x32_bf16(pf[1][mi], vf[1][ni], oacc[mi][ni], 0, 0, 0);
      }
  }

  // epilogue: O[b*T+t][h*64+dh] = oacc / l
  #pragma unroll
  for (int mi = 0; mi < 2; ++mi)
    #pragma unroll
    for (int ni = 0; ni < 4; ++ni)
      #pragma unroll
      for (int j = 0; j < 4; ++j) {
        int trow = rowbase + q0 + w * 32 + mi * 16 + lg * 4 + j;
        int col  = h * 64 + ni * 16 + l15;
        O[(size_t)trow * 1024 + col] = f2bf(oacc[mi][ni][j] / lrun[mi][j]);
      }
}

// ---------------------------------------------------------------------------
extern "C" void kernel_launch(void* const* d_in, const int* in_sizes, int n_in,
                              void* d_out, int out_size, void* d_ws, size_t ws_size,
                              hipStream_t stream) {
  const float* x     = (const float*)d_in[0];   // [4,2048,1024]
  const float* qkv_w = (const float*)d_in[1];   // [3072,1024]
  const float* o_w   = (const float*)d_in[2];   // [1024,1024]
  const float* o_b   = (const float*)d_in[3];   // [1024]

  char* ws = (char*)d_ws;
  short* xb    = (short*)(ws);                                  // 16,777,216 B
  short* wqkvb = (short*)(ws + 16777216);                       //  6,291,456 B
  short* wob   = (short*)(ws + 16777216 + 6291456);             //  2,097,152 B
  short* qkvb  = (short*)(ws + 16777216 + 6291456 + 2097152);   // 50,331,648 B
  short* ob    = (short*)(ws + 16777216 + 6291456 + 2097152 + 50331648); // 16,777,216 B

  cast_f32_bf16<<<8192, 256, 0, stream>>>(x,     xb,    8388608);
  cast_f32_bf16<<<3072, 256, 0, stream>>>(qkv_w, wqkvb, 3145728);
  cast_f32_bf16<<<1024, 256, 0, stream>>>(o_w,   wob,   1048576);

  // qkv = x @ qkv_w^T : M=8192, N=3072, K=1024 -> grid 64*24
  gemm_bt<1><<<1536, 256, 0, stream>>>(xb, wqkvb, (void*)qkvb, nullptr, 8192, 3072, 1024);

  attn_fwd<<<dim3(16, 64), 256, 0, stream>>>(qkvb, ob);

  // out = attn_out @ o_w^T + o_b : M=8192, N=1024, K=1024 -> grid 64*8
  gemm_bt<0><<<512, 256, 0, stream>>>(ob, wob, d_out, o_b, 8192, 1024, 1024);
}

// Round 2
// 218.261 us; speedup vs baseline: 1.5658x; 1.5658x over previous
//
#include <hip/hip_runtime.h>
#include <stdint.h>

// Problem constants: B=4, T=2048, D=1024, NH=16, DH=64
#define TSEQ   2048
#define SCALE_ATTN 0.125f

typedef __attribute__((ext_vector_type(8))) short bf16x8;   // 8 bf16 = 4 VGPRs (MFMA A/B frag)
typedef __attribute__((ext_vector_type(4))) short short4v;
typedef __attribute__((ext_vector_type(4))) float f32x4;    // MFMA C/D frag

__device__ __forceinline__ short f2bf(float f) {  // RNE float->bf16 (finite inputs)
  unsigned u = __float_as_uint(f);
  u = (u + 0x7fffu + ((u >> 16) & 1u)) >> 16;
  return (short)u;
}

__device__ __forceinline__ void async16(const void* gsrc, void* ldst) {
  __builtin_amdgcn_global_load_lds((__attribute__((address_space(1))) void*)(void*)gsrc,
                                   (__attribute__((address_space(3))) void*)ldst, 16, 0, 0);
}

// ---------------------------------------------------------------------------
// cast fp32 -> bf16 (bits in short), vectorized 4/thread
// ---------------------------------------------------------------------------
__global__ void cast_f32_bf16(const float* __restrict__ src, short* __restrict__ dst, int n) {
  int i = (blockIdx.x * blockDim.x + threadIdx.x) * 4;
  if (i >= n) return;
  float4 v = *(const float4*)(src + i);
  short4v o;
  o[0] = f2bf(v.x); o[1] = f2bf(v.y); o[2] = f2bf(v.z); o[3] = f2bf(v.w);
  *(short4v*)(dst + i) = o;
}

// ---------------------------------------------------------------------------
// C = A[M,K] @ B[N,K]^T  (bf16 in, fp32 acc). 128x128 tile, BK=64, 4 waves.
// MODE 0: C fp32 [M][N] + bias[col].
// MODE 2: qkv-split. cols<2048 -> bf16 to Cqk[row][2048]; cols>=2048 (V) ->
//         transposed bf16 to Cvt[(b*16+h)*64+d][2048] (+t), t=row%2048.
// ---------------------------------------------------------------------------
template<int MODE>
__global__ __launch_bounds__(256, 2) void gemm_bt(
    const short* __restrict__ A, const short* __restrict__ B,
    void* __restrict__ C, short* __restrict__ Cvt, const float* __restrict__ bias,
    int M, int N, int K)
{
  __shared__ char ldsA[128 * 128];
  __shared__ char ldsB[128 * 128];

  const int tid  = threadIdx.x;
  const int lane = tid & 63;
  const int w    = tid >> 6;
  const int wrow = w >> 1, wcol = w & 1;
  const int l15  = lane & 15;
  const int klo  = (lane >> 4) << 4;

  // XCD-bijective swizzle (m204); nwg%8==0 for both launches
  int nwg = gridDim.x, orig = blockIdx.x;
  int qq = nwg >> 3, rr = nwg & 7;
  int xcd = orig & 7, lid = orig >> 3;
  int wgid = (xcd < rr ? xcd * (qq + 1) : rr * (qq + 1) + (xcd - rr) * qq) + lid;
  const int nbx = N >> 7;
  const int by = wgid / nbx, bx = wgid - by * nbx;
  const int m0 = by << 7, n0 = bx << 7;

  const char* Abase = (const char*)A + (size_t)m0 * K * 2;
  const char* Bbase = (const char*)B + (size_t)n0 * K * 2;
  const int rowstride = K * 2;

  const int srow  = tid >> 3;
  const int scolb = (tid & 7) << 4;

  f32x4 acc[4][4] = {};

  const int nk = K >> 6;
  for (int kk = 0; kk < nk; ++kk) {
    if (kk) __syncthreads();
    const int kbyte = kk << 7;
    #pragma unroll
    for (int p = 0; p < 4; ++p) {
      int row = p * 32 + srow;
      int sc  = scolb ^ ((row & 7) << 4);     // pre-swizzled source (rule #21)
      async16(Abase + (size_t)row * rowstride + kbyte + sc, ldsA + row * 128 + scolb);
      async16(Bbase + (size_t)row * rowstride + kbyte + sc, ldsB + row * 128 + scolb);
    }
    __syncthreads();

    bf16x8 af[2][4], bf[2][4];
    #pragma unroll
    for (int ks = 0; ks < 2; ++ks)
      #pragma unroll
      for (int mi = 0; mi < 4; ++mi) {
        int row = wrow * 64 + mi * 16 + l15;
        af[ks][mi] = *(const bf16x8*)(ldsA + row * 128 + ((ks * 64 + klo) ^ ((row & 7) << 4)));
      }
    #pragma unroll
    for (int ks = 0; ks < 2; ++ks)
      #pragma unroll
      for (int ni = 0; ni < 4; ++ni) {
        int row = wcol * 64 + ni * 16 + l15;
        bf[ks][ni] = *(const bf16x8*)(ldsB + row * 128 + ((ks * 64 + klo) ^ ((row & 7) << 4)));
      }
    #pragma unroll
    for (int mi = 0; mi < 4; ++mi)
      #pragma unroll
      for (int ni = 0; ni < 4; ++ni) {
        acc[mi][ni] = __builtin_amdgcn_mfma_f32_16x16x32_bf16(af[0][mi], bf[0][ni], acc[mi][ni], 0, 0, 0);
        acc[mi][ni] = __builtin_amdgcn_mfma_f32_16x16x32_bf16(af[1][mi], bf[1][ni], acc[mi][ni], 0, 0, 0);
      }
  }

  // epilogue: C/D layout col=lane&15, row=(lane>>4)*4+j  [m89]
  const int rbase = (lane >> 4) << 2;
  #pragma unroll
  for (int mi = 0; mi < 4; ++mi)
    #pragma unroll
    for (int ni = 0; ni < 4; ++ni) {
      const int col  = n0 + wcol * 64 + ni * 16 + l15;
      const int row0 = m0 + wrow * 64 + mi * 16 + rbase;
      if (MODE == 0) {
        #pragma unroll
        for (int j = 0; j < 4; ++j)
          ((float*)C)[(size_t)(row0 + j) * N + col] = acc[mi][ni][j] + bias[col];
      } else {  // MODE 2
        if (n0 < 2048) {            // Q|K region (block-uniform branch)
          #pragma unroll
          for (int j = 0; j < 4; ++j)
            ((short*)C)[(size_t)(row0 + j) * 2048 + col] = f2bf(acc[mi][ni][j]);
        } else {                    // V region: store transposed Vt[bh*64+d][t]
          short4v o;
          #pragma unroll
          for (int j = 0; j < 4; ++j) o[j] = f2bf(acc[mi][ni][j]);
          const int cv = col - 2048, hh = cv >> 6, dd = cv & 63;
          const int bb = row0 >> 11, t = row0 & 2047;
          *(short4v*)(Cvt + ((size_t)((bb * 16 + hh) * 64 + dd)) * 2048 + t) = o;
        }
      }
    }
}

// ---------------------------------------------------------------------------
// Wave-independent causal flash attention. Block = 1 wave (64 threads) owning
// 32 Q-rows of one (b,h). Zero barriers: Q/K/Vt fragments loaded directly
// from global (row-major 16B frags), only P round-trips per-wave LDS.
// qk: [B*T][2048] bf16 (Q|K per head). vt: [bh*64+d][2048] bf16 (V^T).
// O:  [B*T][1024] bf16.
// ---------------------------------------------------------------------------
__global__ __launch_bounds__(64, 2) void attn_wave(
    const short* __restrict__ qk, const short* __restrict__ vt, short* __restrict__ O)
{
  __shared__ short ldsP[32][72];          // P: [qrow][kv], 144B rows, 2-way banks

  const int lane = threadIdx.x;
  const int l15  = lane & 15;
  const int lg   = lane >> 4;

  // XCD-grouped (L2 locality per head), longest q-blocks dispatched first
  const int bid = blockIdx.x;             // 0..4095
  const int xcd = bid & 7, ii = bid >> 3; // ii 0..511
  const int qb  = 63 - (ii >> 3);         // 0..63, descending work
  const int bh  = xcd * 8 + (ii & 7);     // 8 heads per XCD group
  const int b   = bh >> 4, h = bh & 15;
  const int q0  = qb * 32;
  const int rowbase = b * TSEQ;

  const short* qbase = qk + (size_t)rowbase * 2048 + h * 64 + lg * 8;
  const short* kbase = qbase + 1024;
  const short* vbase = vt + ((size_t)bh * 64 + l15) * 2048 + lg * 8;

  // Q A-frags in registers for the whole kernel: Q[q0+mi*16+l15][ks*32+lg*8..]
  bf16x8 qf[2][2];
  #pragma unroll
  for (int ks = 0; ks < 2; ++ks)
    #pragma unroll
    for (int mi = 0; mi < 2; ++mi)
      qf[ks][mi] = *(const bf16x8*)(qbase + (size_t)(q0 + mi * 16 + l15) * 2048 + ks * 32);

  f32x4 oacc[2][4] = {};
  float mrun[2][4], lrun[2][4];
  #pragma unroll
  for (int mi = 0; mi < 2; ++mi)
    #pragma unroll
    for (int j = 0; j < 4; ++j) { mrun[mi][j] = -1e30f; lrun[mi][j] = 0.f; }

  const int nst = (qb >> 1) + 1;
  for (int s = 0; s < nst; ++s) {
    const int kv0 = s * 64;

    // K B-frags direct from global: K[kv0+ni*16+l15][ks*32+lg*8..]
    bf16x8 kf[2][4];
    #pragma unroll
    for (int ks = 0; ks < 2; ++ks)
      #pragma unroll
      for (int ni = 0; ni < 4; ++ni)
        kf[ks][ni] = *(const bf16x8*)(kbase + (size_t)(kv0 + ni * 16 + l15) * 2048 + ks * 32);

    // Vt B-frags (independent of softmax -> issue early): V[kv0+c*32+lg*8..][ni*16+l15]
    bf16x8 vf[2][4];
    #pragma unroll
    for (int c = 0; c < 2; ++c)
      #pragma unroll
      for (int ni = 0; ni < 4; ++ni)
        vf[c][ni] = *(const bf16x8*)(vbase + (size_t)(ni * 16) * 2048 + kv0 + c * 32);

    // S = Q K^T
    f32x4 sacc[2][4] = {};
    #pragma unroll
    for (int mi = 0; mi < 2; ++mi)
      #pragma unroll
      for (int ni = 0; ni < 4; ++ni) {
        sacc[mi][ni] = __builtin_amdgcn_mfma_f32_16x16x32_bf16(qf[0][mi], kf[0][ni], sacc[mi][ni], 0, 0, 0);
        sacc[mi][ni] = __builtin_amdgcn_mfma_f32_16x16x32_bf16(qf[1][mi], kf[1][ni], sacc[mi][ni], 0, 0, 0);
      }

    // scale + causal mask (only last tile can violate causality)
    const bool diag = (s == nst - 1);
    #pragma unroll
    for (int mi = 0; mi < 2; ++mi)
      #pragma unroll
      for (int ni = 0; ni < 4; ++ni)
        #pragma unroll
        for (int j = 0; j < 4; ++j) {
          float sv = sacc[mi][ni][j] * SCALE_ATTN;
          if (diag) {
            int qrow = q0 + mi * 16 + lg * 4 + j;
            int kcol = kv0 + ni * 16 + l15;
            if (kcol > qrow) sv = -1e30f;
          }
          sacc[mi][ni][j] = sv;
        }

    // wave-parallel row max (16-lane column group shares a row)
    float rmx[2][4];
    #pragma unroll
    for (int mi = 0; mi < 2; ++mi)
      #pragma unroll
      for (int j = 0; j < 4; ++j) {
        float v = fmaxf(fmaxf(sacc[mi][0][j], sacc[mi][1][j]), fmaxf(sacc[mi][2][j], sacc[mi][3][j]));
        v = fmaxf(v, __shfl_xor(v, 1));
        v = fmaxf(v, __shfl_xor(v, 2));
        v = fmaxf(v, __shfl_xor(v, 4));
        v = fmaxf(v, __shfl_xor(v, 8));
        rmx[mi][j] = v;
      }

    // online-softmax: rescale O, emit P (bf16) to per-wave LDS
    #pragma unroll
    for (int mi = 0; mi < 2; ++mi)
      #pragma unroll
      for (int j = 0; j < 4; ++j) {
        float mold = mrun[mi][j];
        float mnew = fmaxf(mold, rmx[mi][j]);
        float alpha = __expf(mold - mnew);
        mrun[mi][j] = mnew;
        float rs = 0.f;
        #pragma unroll
        for (int ni = 0; ni < 4; ++ni) {
          float p = __expf(sacc[mi][ni][j] - mnew);
          rs += p;
          ldsP[mi * 16 + lg * 4 + j][ni * 16 + l15] = f2bf(p);
        }
        rs += __shfl_xor(rs, 1); rs += __shfl_xor(rs, 2);
        rs += __shfl_xor(rs, 4); rs += __shfl_xor(rs, 8);
        lrun[mi][j] = lrun[mi][j] * alpha + rs;
        #pragma unroll
        for (int ni = 0; ni < 4; ++ni) oacc[mi][ni][j] *= alpha;
      }

    asm volatile("" ::: "memory");        // keep P stores before P loads

    // O += P @ V
    bf16x8 pf[2][2];
    #pragma unroll
    for (int c = 0; c < 2; ++c)
      #pragma unroll
      for (int mi = 0; mi < 2; ++mi)
        pf[c][mi] = *(const bf16x8*)((const char*)&ldsP[mi * 16 + l15][0] + c * 64 + lg * 16);
    #pragma unroll
    for (int mi = 0; mi < 2; ++mi)
      #pragma unroll
      for (int ni = 0; ni < 4; ++ni) {
        oacc[mi][ni] = __builtin_amdgcn_mfma_f32_16x16x32_bf16(pf[0][mi], vf[0][ni], oacc[mi][ni], 0, 0, 0);
        oacc[mi][ni] = __builtin_amdgcn_mfma_f32_16x16x32_bf16(pf[1][mi], vf[1][ni], oacc[mi][ni], 0, 0, 0);
      }
  }

  // epilogue: O[b*T+t][h*64+dh] = oacc / l
  #pragma unroll
  for (int mi = 0; mi < 2; ++mi)
    #pragma unroll
    for (int ni = 0; ni < 4; ++ni)
      #pragma unroll
      for (int j = 0; j < 4; ++j) {
        int trow = rowbase + q0 + mi * 16 + lg * 4 + j;
        int col  = h * 64 + ni * 16 + l15;
        O[(size_t)trow * 1024 + col] = f2bf(oacc[mi][ni][j] / lrun[mi][j]);
      }
}

// ---------------------------------------------------------------------------
extern "C" void kernel_launch(void* const* d_in, const int* in_sizes, int n_in,
                              void* d_out, int out_size, void* d_ws, size_t ws_size,
                              hipStream_t stream) {
  const float* x     = (const float*)d_in[0];   // [4,2048,1024]
  const float* qkv_w = (const float*)d_in[1];   // [3072,1024]
  const float* o_w   = (const float*)d_in[2];   // [1024,1024]
  const float* o_b   = (const float*)d_in[3];   // [1024]

  char* ws = (char*)d_ws;
  short* xb    = (short*)(ws);                   // 16 MB  [8192][1024] bf16
  short* wqkvb = (short*)(ws + 16777216);        //  6 MB  [3072][1024]
  short* wob   = (short*)(ws + 23068672);        //  2 MB  [1024][1024]
  short* qkb   = (short*)(ws + 25165824);        // 32 MB  [8192][2048]  Q|K
  short* vtb   = (short*)(ws + 58720256);        // 16 MB  [64*64][2048] V^T
  short* ob    = (short*)(ws + 75497472);        // 16 MB  [8192][1024]  attn out
  // total 88 MB (< round-1's 92 MB usage)

  cast_f32_bf16<<<8192, 256, 0, stream>>>(x,     xb,    8388608);
  cast_f32_bf16<<<3072, 256, 0, stream>>>(qkv_w, wqkvb, 3145728);
  cast_f32_bf16<<<1024, 256, 0, stream>>>(o_w,   wob,   1048576);

  // qkv = x @ qkv_w^T : M=8192, N=3072, K=1024; Q|K row-major, V transposed
  gemm_bt<2><<<1536, 256, 0, stream>>>(xb, wqkvb, (void*)qkb, vtb, nullptr, 8192, 3072, 1024);

  attn_wave<<<4096, 64, 0, stream>>>(qkb, vtb, ob);

  // out = attn_out @ o_w^T + o_b : M=8192, N=1024, K=1024
  gemm_bt<0><<<512, 256, 0, stream>>>(ob, wob, d_out, nullptr, o_b, 8192, 1024, 1024);
}